// Round 4
// baseline (493.916 us; speedup 1.0000x reference)
//
#include <hip/hip_runtime.h>
#include <hip/hip_bf16.h>

#define ENC_DIM 2048
#define DEC_DIM 512
#define ATT_DIM 512
#define BATCH   128
#define NPIX    196
#define NROWS   (BATCH * NPIX)   // 25088

typedef short bf16x8 __attribute__((ext_vector_type(8)));
typedef float f32x4  __attribute__((ext_vector_type(4)));
typedef unsigned short u16x8 __attribute__((ext_vector_type(8)));

__device__ __forceinline__ unsigned short f2bf(float f) {
    union { float f; unsigned u; } v; v.f = f;
    unsigned r = v.u + 0x7fffu + ((v.u >> 16) & 1u);   // RNE
    return (unsigned short)(r >> 16);
}

// ---------------------------------------------------------------- k0:
// Wt[a][e] = bf16(W_enc[e][a])  (2048x512 -> 512x2048), LDS-tiled transpose.
__global__ void k0_transpose(const float* __restrict__ W_enc,
                             unsigned short* __restrict__ Wt) {
    __shared__ float ts[64][65];
    const int a0 = blockIdx.x * 64;      // grid.x = 8
    const int e0 = blockIdx.y * 64;      // grid.y = 32
    const int tx = threadIdx.x & 15;
    const int ty = threadIdx.x >> 4;     // 16x16 threads
    #pragma unroll
    for (int p = 0; p < 4; ++p) {
        const int e = ty + p * 16;
        const float4 v = *(const float4*)&W_enc[(size_t)(e0 + e) * ATT_DIM + a0 + tx * 4];
        ts[e][tx * 4 + 0] = v.x; ts[e][tx * 4 + 1] = v.y;
        ts[e][tx * 4 + 2] = v.z; ts[e][tx * 4 + 3] = v.w;
    }
    __syncthreads();
    #pragma unroll
    for (int p = 0; p < 4; ++p) {
        const int a = ty + p * 16;
        ushort4 u;
        u.x = f2bf(ts[tx * 4 + 0][a]);
        u.y = f2bf(ts[tx * 4 + 1][a]);
        u.z = f2bf(ts[tx * 4 + 2][a]);
        u.w = f2bf(ts[tx * 4 + 3][a]);
        *(ushort4*)&Wt[(size_t)(a0 + a) * ENC_DIM + e0 + tx * 4] = u;
    }
}

// ---------------------------------------------------------------- k1:
// att2'[b][a] = dh[b,:]@W_dec[:,a] + b_dec[a] + b_enc[a];  att[r] = b_full;
// also zero-init awe (k4 accumulates with atomics).
// grid (2 col-halves, 128 batches) x 256 thr.
__global__ void k1_att2(const float* __restrict__ dh, const float* __restrict__ W_dec,
                        const float* __restrict__ b_dec, const float* __restrict__ b_enc,
                        const float* __restrict__ b_full,
                        float* __restrict__ att2, float* __restrict__ att,
                        float* __restrict__ awe) {
    __shared__ float dhs[DEC_DIM];
    const int c = blockIdx.x, b = blockIdx.y, t = threadIdx.x;
    const f32x4 z = {0.f, 0.f, 0.f, 0.f};
    *(f32x4*)&awe[(size_t)b * ENC_DIM + c * 1024 + t * 4] = z;
    dhs[t]       = dh[b * DEC_DIM + t];
    dhs[t + 256] = dh[b * DEC_DIM + t + 256];
    __syncthreads();
    const int col = c * 256 + t;
    float acc = 0.f;
    for (int d = 0; d < DEC_DIM; ++d)
        acc += dhs[d] * W_dec[d * ATT_DIM + col];
    att2[b * ATT_DIM + col] = acc + b_dec[col] + b_enc[col];
    const int gid = (b * 2 + c) * 256 + t;
    if (gid < NROWS) att[gid] = b_full[0];
}

// ---------------------------------------------------------------- k2:
// Fused bf16 MFMA GEMM + relu + W_full reduction -> atomic partial scores.
// BM=64, BN=256, BK=64. grid (2 n-tiles, 392 m-tiles) = 784 blocks.
// LDS row stride 72 shorts (144 B, odd multiple of 16 B -> phase-conflict-
// free b128 access). A read ~2x logical (adjacent n-tiles -> L3 absorbs).
__launch_bounds__(256, 3)
__global__ void k2_gemm(const float* __restrict__ enc, const unsigned short* __restrict__ Wt,
                        const float* __restrict__ att2, const float* __restrict__ W_full,
                        float* __restrict__ att) {
    __shared__ __align__(16) unsigned short As[64 * 72];    //  9.2 KB
    __shared__ __align__(16) unsigned short Bs[256 * 72];   // 36.9 KB
    __shared__ float att2s[2][256];
    __shared__ float wfs[256];

    const int t    = threadIdx.x;
    const int n0   = blockIdx.x * 256;
    const int row0 = blockIdx.y * 64;
    const int b0   = row0 / NPIX;
    const int rows_left = (b0 + 1) * NPIX - row0;   // rows in this tile with batch b0

    att2s[0][t] = att2[b0 * ATT_DIM + n0 + t];
    att2s[1][t] = (b0 + 1 < BATCH) ? att2[(b0 + 1) * ATT_DIM + n0 + t] : 0.f;
    wfs[t]      = W_full[n0 + t];

    const int w    = t >> 6;          // wave 0..3
    const int lane = t & 63;
    const int q    = lane >> 4;       // 0..3
    const int cl   = lane & 15;
    const int wm   = (w >> 1) * 32;   // wave's row offset (0/32)
    const int wn   = (w & 1) * 128;   // wave's col offset (0/128)

    f32x4 acc[2][8] = {};

    // staging assignments (BK=64)
    const int ar = t >> 2;            // A row 0..63
    const int ak = (t & 3) * 16;      // A k 0,16,32,48 (16 floats / thread)

    const float*          encA = enc + (size_t)(row0 + ar) * ENC_DIM + ak;
    const unsigned short* WtB  = Wt  + (size_t)(n0 + t)    * ENC_DIM;      // one B row / thread

    for (int k0 = 0; k0 < ENC_DIM; k0 += 64) {
        __syncthreads();   // previous iteration's frag reads complete
        // stage A (fp32 -> bf16): 64 x 64
        {
            const float4 v0 = *(const float4*)(encA + k0);
            const float4 v1 = *(const float4*)(encA + k0 + 4);
            const float4 v2 = *(const float4*)(encA + k0 + 8);
            const float4 v3 = *(const float4*)(encA + k0 + 12);
            u16x8 ua, ub;
            ua[0] = f2bf(v0.x); ua[1] = f2bf(v0.y); ua[2] = f2bf(v0.z); ua[3] = f2bf(v0.w);
            ua[4] = f2bf(v1.x); ua[5] = f2bf(v1.y); ua[6] = f2bf(v1.z); ua[7] = f2bf(v1.w);
            ub[0] = f2bf(v2.x); ub[1] = f2bf(v2.y); ub[2] = f2bf(v2.z); ub[3] = f2bf(v2.w);
            ub[4] = f2bf(v3.x); ub[5] = f2bf(v3.y); ub[6] = f2bf(v3.z); ub[7] = f2bf(v3.w);
            *(u16x8*)&As[ar * 72 + ak]     = ua;
            *(u16x8*)&As[ar * 72 + ak + 8] = ub;
        }
        // stage B (bf16): 256 x 64, one row per thread (128 B = 8 x uint4)
        #pragma unroll
        for (int j = 0; j < 8; ++j) {
            const uint4 v = *(const uint4*)(WtB + k0 + j * 8);
            *(uint4*)&Bs[t * 72 + j * 8] = v;
        }
        __syncthreads();   // tile visible

        #pragma unroll
        for (int h = 0; h < 2; ++h) {   // two 32-wide K halves
            bf16x8 af[2], bfr[8];
            #pragma unroll
            for (int i = 0; i < 2; ++i)
                af[i]  = *(const bf16x8*)&As[(wm + i * 16 + cl) * 72 + h * 32 + q * 8];
            #pragma unroll
            for (int i = 0; i < 8; ++i)
                bfr[i] = *(const bf16x8*)&Bs[(wn + i * 16 + cl) * 72 + h * 32 + q * 8];
            #pragma unroll
            for (int mi = 0; mi < 2; ++mi)
                #pragma unroll
                for (int ni = 0; ni < 8; ++ni)
                    acc[mi][ni] = __builtin_amdgcn_mfma_f32_16x16x32_bf16(
                        af[mi], bfr[ni], acc[mi][ni], 0, 0, 0);
        }
    }

    // Epilogue: relu(att1 + att2') * W_full, reduce over this block's 256 cols.
    #pragma unroll
    for (int mi = 0; mi < 2; ++mi) {
        float rs[4];
        #pragma unroll
        for (int i = 0; i < 4; ++i) {
            const int lr  = wm + mi * 16 + q * 4 + i;         // local row
            const int sel = (lr >= rows_left) ? 1 : 0;
            float sum = 0.f;
            #pragma unroll
            for (int ni = 0; ni < 8; ++ni) {
                const int j = wn + ni * 16 + cl;              // local col 0..255
                float v = acc[mi][ni][i] + att2s[sel][j];
                v = fmaxf(v, 0.f);
                sum += v * wfs[j];
            }
            rs[i] = sum;
        }
        #pragma unroll
        for (int o = 1; o < 16; o <<= 1) {
            #pragma unroll
            for (int i = 0; i < 4; ++i) rs[i] += __shfl_xor(rs[i], o);
        }
        if (cl == 0) {
            #pragma unroll
            for (int i = 0; i < 4; ++i) {
                const int r = row0 + wm + mi * 16 + q * 4 + i;
                atomicAdd(&att[r], rs[i]);
            }
        }
    }
}

// ---------------------------------------------------------------- k3:
// softmax over P=196, in place. 128 blocks x 256 thr.
__global__ void k3_softmax(float* __restrict__ att_alpha) {
    __shared__ float red[4];
    const int b = blockIdx.x, t = threadIdx.x;
    const int w = t >> 6, lane = t & 63;
    const float x = (t < NPIX) ? att_alpha[b * NPIX + t] : -INFINITY;
    float m = x;
    #pragma unroll
    for (int o = 32; o >= 1; o >>= 1) m = fmaxf(m, __shfl_xor(m, o));
    if (lane == 0) red[w] = m;
    __syncthreads();
    m = fmaxf(fmaxf(red[0], red[1]), fmaxf(red[2], red[3]));
    const float e = (t < NPIX) ? __expf(x - m) : 0.f;
    float s = e;
    #pragma unroll
    for (int o = 32; o >= 1; o >>= 1) s += __shfl_xor(s, o);
    __syncthreads();
    if (lane == 0) red[w] = s;
    __syncthreads();
    s = red[0] + red[1] + red[2] + red[3];
    if (t < NPIX) att_alpha[b * NPIX + t] = e / s;
}

// ---------------------------------------------------------------- k4:
// awe[b][e] += sum_{p in half} alpha[b][p] * enc[b][p][e].
// grid (4 e-chunks, 2 p-halves, 128 b) x 128 thr = 1024 blocks (8 waves/CU).
// awe zero-initialized by k1.
__global__ void k4_awe(const float* __restrict__ enc, const float* __restrict__ alpha,
                       float* __restrict__ awe) {
    __shared__ float as[98];
    const int b  = blockIdx.z;
    const int p0 = blockIdx.y * 98;
    const int t  = threadIdx.x;
    const int e0 = blockIdx.x * 512 + t * 4;
    if (t < 98) as[t] = alpha[b * NPIX + p0 + t];
    __syncthreads();
    const float* base = enc + ((size_t)b * NPIX + p0) * ENC_DIM + e0;
    f32x4 a[8] = {};
    for (int p = 0; p < 96; p += 8) {
        #pragma unroll
        for (int j = 0; j < 8; ++j) {
            const f32x4 v = *(const f32x4*)(base + (size_t)(p + j) * ENC_DIM);
            a[j] += as[p + j] * v;
        }
    }
    {   // tail: pixels 96, 97
        const f32x4 v0 = *(const f32x4*)(base + (size_t)96 * ENC_DIM);
        const f32x4 v1 = *(const f32x4*)(base + (size_t)97 * ENC_DIM);
        a[0] += as[96] * v0;
        a[1] += as[97] * v1;
    }
    const f32x4 r = ((a[0] + a[1]) + (a[2] + a[3])) + ((a[4] + a[5]) + (a[6] + a[7]));
    float* dst = &awe[(size_t)b * ENC_DIM + e0];
    atomicAdd(dst + 0, r[0]);
    atomicAdd(dst + 1, r[1]);
    atomicAdd(dst + 2, r[2]);
    atomicAdd(dst + 3, r[3]);
}

// ----------------------------------------------------------------
extern "C" void kernel_launch(void* const* d_in, const int* in_sizes, int n_in,
                              void* d_out, int out_size, void* d_ws, size_t ws_size,
                              hipStream_t stream) {
    const float* enc    = (const float*)d_in[0];   // [128,196,2048]
    const float* dh     = (const float*)d_in[1];   // [128,512]
    const float* W_enc  = (const float*)d_in[2];   // [2048,512]
    const float* b_enc  = (const float*)d_in[3];   // [512]
    const float* W_dec  = (const float*)d_in[4];   // [512,512]
    const float* b_dec  = (const float*)d_in[5];   // [512]
    const float* W_full = (const float*)d_in[6];   // [512]
    const float* b_full = (const float*)d_in[7];   // scalar

    float* awe   = (float*)d_out;                  // [128,2048]
    float* alpha = awe + BATCH * ENC_DIM;          // [128,196]; also score scratch

    // workspace: Wt bf16 (2 MB) + att2' fp32 (256 KB) = 2.25 MB
    unsigned short* Wt   = (unsigned short*)d_ws;
    float*          att2 = (float*)((char*)d_ws + (size_t)ATT_DIM * ENC_DIM * 2);

    k0_transpose<<<dim3(8, 32),     256, 0, stream>>>(W_enc, Wt);
    k1_att2     <<<dim3(2, 128),    256, 0, stream>>>(dh, W_dec, b_dec, b_enc, b_full, att2, alpha, awe);
    k2_gemm     <<<dim3(2, 392),    256, 0, stream>>>(enc, Wt, att2, W_full, alpha);
    k3_softmax  <<<128,             256, 0, stream>>>(alpha);
    k4_awe      <<<dim3(4, 2, 128), 128, 0, stream>>>(enc, alpha, awe);
}